// Round 1
// baseline (188.819 us; speedup 1.0000x reference)
//
#include <hip/hip_runtime.h>

typedef __attribute__((ext_vector_type(8))) short short8;
typedef __attribute__((ext_vector_type(4))) float floatx4;

// fp32 -> bf16 round-to-nearest-even (inputs are finite; no NaN handling needed)
static __device__ __forceinline__ unsigned short f2bf(float f) {
    union { float f; unsigned int u; } v; v.f = f;
    unsigned int u = v.u;
    return (unsigned short)((u + 0x7FFFu + ((u >> 16) & 1u)) >> 16);
}

// node_emb fp32 [N*128] -> bf16 bits, vectorized float4 -> ushort4
__global__ void cvt_nodes_kernel(const float* __restrict__ x,
                                 unsigned short* __restrict__ y, int n4) {
    int i = blockIdx.x * blockDim.x + threadIdx.x;
    if (i >= n4) return;
    const float4 v = ((const float4*)x)[i];
    ushort4 o;
    o.x = f2bf(v.x); o.y = f2bf(v.y); o.z = f2bf(v.z); o.w = f2bf(v.w);
    ((ushort4*)y)[i] = o;
}

// W1 fp32 [256,128] -> W1^T bf16 [128,256]  (w1t[n*256+k] = W1[k*128+n])
__global__ void cvt_w1t_kernel(const float* __restrict__ w1,
                               unsigned short* __restrict__ w1t) {
    int t = blockIdx.x * blockDim.x + threadIdx.x;  // 0..32767, coalesced read
    int k = t >> 7;
    int n = t & 127;
    w1t[n * 256 + k] = f2bf(w1[t]);
}

#define LDSW 136  // 128 + 8 pad: row stride 272B = 68 words === 4 (mod 32) -> uniform banks

__global__ __launch_bounds__(256, 2) void edge_mlp_kernel(
    const unsigned short* __restrict__ nodes,  // [N,128] bf16 bits
    const unsigned short* __restrict__ w1t,    // [128,256] bf16 bits (W1^T)
    const int* __restrict__ eidx,              // [2,E] int32
    const float* __restrict__ b1,              // [128]
    const float* __restrict__ w2,              // [128,2]
    const float* __restrict__ b2,              // [2]
    float* __restrict__ out,                   // [E,2]
    int E, int n_nodes)
{
    __shared__ unsigned short sB[128 * LDSW];  // 34816 B: one BK=128 chunk of W1^T

    const int tid = threadIdx.x;
    const int lane = tid & 63;
    const int wave = tid >> 6;
    const int l15 = lane & 15;          // A row / B col / C col lane index
    const int lq  = lane >> 4;          // k-quad
    const long e0 = (long)blockIdx.x * 256 + (long)wave * 64;

    // Per-lane gather byte offsets for the 4 row-tiles this wave owns.
    int offs[4], offd[4];
#pragma unroll
    for (int rt = 0; rt < 4; rt++) {
        long e = e0 + rt * 16 + l15;
        if (e >= E) e = E - 1;
        int s = eidx[e];
        int d = eidx[(long)E + e];
        s = (s < 0) ? 0 : (s >= n_nodes ? n_nodes - 1 : s);  // safety clamp
        d = (d < 0) ? 0 : (d >= n_nodes ? n_nodes - 1 : d);
        offs[rt] = s << 8;   // *256 bytes per node row (128 bf16)
        offd[rt] = d << 8;
    }
    const char* nbase = (const char*)nodes;
    const int lko = lq * 16;  // lane byte offset within a 32-element k-chunk

    floatx4 acc[4][8];
#pragma unroll
    for (int rt = 0; rt < 4; rt++)
#pragma unroll
        for (int t = 0; t < 8; t++) acc[rt][t] = (floatx4){0.f, 0.f, 0.f, 0.f};

    short8 a_cur[4], a_nxt[4];
#pragma unroll
    for (int rt = 0; rt < 4; rt++)
        a_cur[rt] = *(const short8*)(nbase + offs[rt] + lko);  // kstep 0 (src half)

    for (int ch = 0; ch < 2; ch++) {
        if (ch) __syncthreads();  // all reads of previous chunk done before overwrite
        // stage W1^T chunk ch: 128 rows x 128 k -> LDS (16B per thread-chunk)
        for (int c = tid; c < 2048; c += 256) {
            int n = c >> 4, kk = (c & 15) << 3;
            *(short8*)(&sB[n * LDSW + kk]) =
                *(const short8*)(&w1t[n * 256 + ch * 128 + kk]);
        }
        __syncthreads();

#pragma unroll
        for (int k2 = 0; k2 < 4; k2++) {
            const int ks = ch * 4 + k2;
            if (ks < 7) {  // double-buffer next A fragment from global
                const int ksn = ks + 1;
                const int cb = ((ksn & 3) * 64) + lko;
#pragma unroll
                for (int rt = 0; rt < 4; rt++)
                    a_nxt[rt] = *(const short8*)(
                        nbase + ((ksn < 4) ? offs[rt] : offd[rt]) + cb);
            }
            const int bko = k2 * 32 + lq * 8;
#pragma unroll
            for (int t = 0; t < 8; t++) {
                short8 b = *(const short8*)(&sB[(t * 16 + l15) * LDSW + bko]);
#pragma unroll
                for (int rt = 0; rt < 4; rt++)
                    acc[rt][t] = __builtin_amdgcn_mfma_f32_16x16x32_bf16(
                        a_cur[rt], b, acc[rt][t], 0, 0, 0);
            }
#pragma unroll
            for (int rt = 0; rt < 4; rt++) a_cur[rt] = a_nxt[rt];
        }
    }

    // Epilogue: h = relu(acc + b1); out = h @ W2 + b2, fp32 throughout.
    float b1v[8], w20[8], w21[8];
#pragma unroll
    for (int t = 0; t < 8; t++) {
        int c = t * 16 + l15;
        b1v[t] = b1[c];
        w20[t] = w2[c * 2];
        w21[t] = w2[c * 2 + 1];
    }
    const float bias0 = b2[0], bias1 = b2[1];
#pragma unroll
    for (int rt = 0; rt < 4; rt++) {
#pragma unroll
        for (int i = 0; i < 4; i++) {
            float p0 = 0.f, p1 = 0.f;
#pragma unroll
            for (int t = 0; t < 8; t++) {
                float h = acc[rt][t][i] + b1v[t];
                h = fmaxf(h, 0.f);
                p0 = fmaf(h, w20[t], p0);
                p1 = fmaf(h, w21[t], p1);
            }
            // reduce across the 16 col-lanes (xor masks stay within the group)
#pragma unroll
            for (int m = 1; m < 16; m <<= 1) {
                p0 += __shfl_xor(p0, m, 64);
                p1 += __shfl_xor(p1, m, 64);
            }
            if (l15 == 0) {
                long e = e0 + rt * 16 + lq * 4 + i;
                if (e < E) {
                    float2 o;
                    o.x = p0 + bias0;
                    o.y = p1 + bias1;
                    *(float2*)(&out[e * 2]) = o;
                }
            }
        }
    }
}

extern "C" void kernel_launch(void* const* d_in, const int* in_sizes, int n_in,
                              void* d_out, int out_size, void* d_ws, size_t ws_size,
                              hipStream_t stream) {
    const float* node_emb = (const float*)d_in[0];
    const int*   eidx     = (const int*)d_in[1];
    const float* W1       = (const float*)d_in[2];
    const float* b1       = (const float*)d_in[3];
    const float* W2       = (const float*)d_in[4];
    const float* b2       = (const float*)d_in[5];
    float* out = (float*)d_out;

    const int n_node_elems = in_sizes[0];        // N*128
    const int n_nodes = n_node_elems / 128;
    const int E = in_sizes[1] / 2;

    unsigned short* nodes_bf16 = (unsigned short*)d_ws;
    unsigned short* w1t =
        (unsigned short*)((char*)d_ws + (size_t)n_node_elems * 2);

    const int n4 = n_node_elems / 4;
    cvt_nodes_kernel<<<(n4 + 255) / 256, 256, 0, stream>>>(node_emb, nodes_bf16, n4);
    cvt_w1t_kernel<<<128, 256, 0, stream>>>(W1, w1t);

    const int nblk = (E + 255) / 256;
    edge_mlp_kernel<<<nblk, 256, 0, stream>>>(nodes_bf16, w1t, eidx,
                                              b1, W2, b2, out, E, n_nodes);
}